// Round 4
// baseline (667.765 us; speedup 1.0000x reference)
//
#include <hip/hip_runtime.h>
#include <stdint.h>

typedef uint32_t u32; typedef uint64_t u64; typedef unsigned short u16;

// Problem geometry
#define NB   64
#define NC   256
#define NG   4
#define HW   784      // 28*28
#define PHW  900      // 30*30 padded
#define NTOT 12845056 // 64*256*784

// Workspace layout (bytes); total footprint = 18,637,824 B
#define OFF_XMAX 0
#define OFF_FLG1 64                       // 256 u32: zero-flag per n*4+g (layer-1 acts)
#define OFF_FLG2 1088                     // 64 u32: zero-flag per n (layer-2 acts)
#define OFF_W1P  2048                     // [oc(256)][i(4)][tap(9)] u64 = 73728
#define OFF_W2P  75776                    // [oc(256)][tap(9)][icw(4)] u64 = 73728
#define OFF_A1   149504                   // [oc*4+i] f32
#define OFF_S1   153600
#define OFF_A2   157696                   // [oc] f32
#define OFF_S2   158720
#define OFF_C1   159744                   // [(oc*4+i)*9+pat] f32 = 36864
#define OFF_C2   196608                   // [oc*9+pat] f32 = 9216
#define OFF_BA1  205824                   // [i(4)][n(64)][g(4)][900] u64 = 7372800
#define OFF_BZ1  7578624                  // zero-masks, same layout as BA1
#define OFF_BA2  14951424                 // [n(64)][icw(4)][900] u64 = 1843200
#define OFF_BZ2  16794624                 // zero-masks, same layout as BA2

__device__ inline double wredsumd(double v) {
#pragma unroll
    for (int off = 32; off; off >>= 1) v += __shfl_xor(v, off);
    return v;
}

// ---------------- K0: max|x| ----------------
__global__ __launch_bounds__(256) void k_absmax(const float4* __restrict__ x, u32* __restrict__ xmax, int n4) {
    u32 m = 0;
    int idx = blockIdx.x * blockDim.x + threadIdx.x;
    int stride = gridDim.x * blockDim.x;
    for (int i = idx; i < n4; i += stride) {
        float4 v = x[i];
        m = max(m, __float_as_uint(v.x) & 0x7fffffffu);
        m = max(m, __float_as_uint(v.y) & 0x7fffffffu);
        m = max(m, __float_as_uint(v.z) & 0x7fffffffu);
        m = max(m, __float_as_uint(v.w) & 0x7fffffffu);
    }
#pragma unroll
    for (int off = 32; off; off >>= 1) {
        u32 o = (u32)__shfl_xor((int)m, off);
        m = max(m, o);
    }
    __shared__ u32 sm[4];
    int lane = threadIdx.x & 63, wid = threadIdx.x >> 6;
    if (lane == 0) sm[wid] = m;
    __syncthreads();
    if (threadIdx.x == 0) {
        u32 mm = max(max(sm[0], sm[1]), max(sm[2], sm[3]));
        atomicMax(xmax, mm);
    }
}

// ---------------- K1: prep layer-1 weights (f64 stats) ----------------
__global__ __launch_bounds__(256) void k_prep1(const float* __restrict__ w1, const float* __restrict__ g1,
                                               const float* __restrict__ b1, const float* __restrict__ m1,
                                               const float* __restrict__ v1, char* __restrict__ ws) {
    int lane = threadIdx.x & 63, wid = threadIdx.x >> 6;
    int cc = blockIdx.x * 4 + wid;        // 0..1023
    int i = cc >> 8, oc = cc & 255;       // branch, global out-channel
    const float* wp = w1 + ((size_t)(i * 256 + oc) * 64 + lane) * 9;
    float v[9];
#pragma unroll
    for (int t = 0; t < 9; t++) v[t] = wp[t];
    double s = 0.0;
#pragma unroll
    for (int t = 0; t < 9; t++) s += (double)v[t];
    s = wredsumd(s);
    double mean = s / 576.0;
    double ssq = 0.0, sab = 0.0;
#pragma unroll
    for (int t = 0; t < 9; t++) { double d = (double)v[t] - mean; ssq += d * d; sab += fabs(d); }
    ssq = wredsumd(ssq); sab = wredsumd(sab);
    double stdv = sqrt(ssq / 575.0);
    double meanabs = sab / 576.0 / stdv;
    float scale = (float)exp2(rint(log2(meanabs)));   // exact power of 2
    int bi = i * 256 + oc;
    float inv = __fdiv_rn(g1[bi], __fsqrt_rn(__fadd_rn(v1[bi], 1e-5f)));
    float A = __fmul_rn(scale, inv);      // exact: scale is a power of 2
    float S = __fsub_rn(b1[bi], __fmul_rn(m1[bi], inv));

    u64* w1p = (u64*)(ws + OFF_W1P);
    int c[9]; u64 keep = 0;
#pragma unroll
    for (int t = 0; t < 9; t++) {
        u64 bal = __ballot((double)v[t] > mean);
        c[t] = 64 - 2 * (int)__popcll(bal);   // = -sum of weight signs at tap t
        if (lane == t) keep = bal;
    }
    if (lane < 9) w1p[(size_t)(oc * 4 + i) * 9 + lane] = keep;
    if (lane == 0) {
        ((float*)(ws + OFF_A1))[oc * 4 + i] = A;
        ((float*)(ws + OFF_S1))[oc * 4 + i] = S;
        float* C1 = (float*)(ws + OFF_C1);
#pragma unroll
        for (int pat = 0; pat < 9; pat++) {
            int rt = pat / 3, ct = pat % 3, corr = 0;
#pragma unroll
            for (int t = 0; t < 9; t++) {
                int dh = t / 3 - 1, dw = t % 3 - 1;
                bool inval = (rt == 0 && dh < 0) || (rt == 2 && dh > 0) || (ct == 0 && dw < 0) || (ct == 2 && dw > 0);
                if (inval) corr += c[t];
            }
            C1[(oc * 4 + i) * 9 + pat] = (float)(576 - corr);
        }
    }
}

// ---------------- K2: prep layer-2 weights (f64 stats) ----------------
__global__ __launch_bounds__(256) void k_prep2(const float* __restrict__ w2, const float* __restrict__ g2,
                                               const float* __restrict__ b2, const float* __restrict__ m2,
                                               const float* __restrict__ v2, char* __restrict__ ws) {
    int lane = threadIdx.x & 63, wid = threadIdx.x >> 6;
    int oc = blockIdx.x * 4 + wid;        // 0..255
    float v[36];
#pragma unroll
    for (int icw = 0; icw < 4; icw++)
#pragma unroll
        for (int t = 0; t < 9; t++)
            v[icw * 9 + t] = w2[(size_t)(oc * 256 + icw * 64 + lane) * 9 + t];
    double s = 0.0;
#pragma unroll
    for (int k = 0; k < 36; k++) s += (double)v[k];
    s = wredsumd(s);
    double mean = s / 2304.0;
    double ssq = 0.0, sab = 0.0;
#pragma unroll
    for (int k = 0; k < 36; k++) { double d = (double)v[k] - mean; ssq += d * d; sab += fabs(d); }
    ssq = wredsumd(ssq); sab = wredsumd(sab);
    double stdv = sqrt(ssq / 2303.0);
    double meanabs = sab / 2304.0 / stdv;
    float scale = (float)exp2(rint(log2(meanabs)));
    float inv = __fdiv_rn(g2[oc], __fsqrt_rn(__fadd_rn(v2[oc], 1e-5f)));
    float A = __fmul_rn(scale, inv);
    float S = __fsub_rn(b2[oc], __fmul_rn(m2[oc], inv));

    u64* w2p = (u64*)(ws + OFF_W2P);
    int c2[9] = {0,0,0,0,0,0,0,0,0};
    u64 keep = 0;
#pragma unroll
    for (int icw = 0; icw < 4; icw++)
#pragma unroll
        for (int t = 0; t < 9; t++) {
            u64 bal = __ballot((double)v[icw * 9 + t] > mean);
            c2[t] += 64 - 2 * (int)__popcll(bal);
            if (lane == t * 4 + icw) keep = bal;
        }
    if (lane < 36) w2p[(size_t)oc * 36 + lane] = keep;
    if (lane == 0) {
        ((float*)(ws + OFF_A2))[oc] = A;
        ((float*)(ws + OFF_S2))[oc] = S;
        float* C2 = (float*)(ws + OFF_C2);
#pragma unroll
        for (int pat = 0; pat < 9; pat++) {
            int rt = pat / 3, ct = pat % 3, corr = 0;
#pragma unroll
            for (int t = 0; t < 9; t++) {
                int dh = t / 3 - 1, dw = t % 3 - 1;
                bool inval = (rt == 0 && dh < 0) || (rt == 2 && dh > 0) || (ct == 0 && dw < 0) || (ct == 2 && dw > 0);
                if (inval) corr += c2[t];
            }
            C2[oc * 9 + pat] = (float)(2304 - corr);
        }
    }
}

// ---------------- K3: pack 4 shifted sign-activations + zero masks (zero halo) ----------------
__global__ __launch_bounds__(256) void k_pack(const float* __restrict__ x, char* __restrict__ ws) {
    int g = blockIdx.x / 225, bb = blockIdx.x % 225;
    int fp = bb * 256 + threadIdx.x;      // 0..57599 = n*900+idx
    int n = fp / 900, idx = fp - n * 900;
    int ph = idx / 30, pw = idx - ph * 30;
    u64* ba1 = (u64*)(ws + OFF_BA1);
    u64* bz1 = (u64*)(ws + OFF_BZ1);
    bool halo = (ph == 0) | (ph == 29) | (pw == 0) | (pw == 29);
    if (halo) {
#pragma unroll
        for (int i = 0; i < 4; i++) {
            size_t o = (size_t)((i * 64 + n) * 4 + g) * 900 + idx;
            ba1[o] = 0; bz1[o] = 0;
        }
        ((u64*)(ws + OFF_BA2))[(size_t)(n * 4 + g) * 900 + idx] = 0;
        ((u64*)(ws + OFF_BZ2))[(size_t)(n * 4 + g) * 900 + idx] = 0;
        return;
    }
    float xmax = *(const float*)(ws + OFF_XMAX);    // bits of max|x| == value
    float t0 = __fmul_rn(-0.6f, xmax), t1 = __fmul_rn(-0.2f, xmax);
    float t2 = __fmul_rn(0.2f, xmax), t3 = __fmul_rn(0.6f, xmax);
    int h = ph - 1, w = pw - 1;
    const float* xb = x + (size_t)(n * 256 + g * 64) * 784 + (h * 28 + w);
    u64 wd0 = 0, wd1 = 0, wd2 = 0, wd3 = 0;
    u64 zd0 = 0, zd1 = 0, zd2 = 0, zd3 = 0;
#pragma unroll 8
    for (int c = 0; c < 64; c++) {
        float v = xb[(size_t)c * 784];
        float s0 = __fadd_rn(v, t0), s1 = __fadd_rn(v, t1);
        float s2 = __fadd_rn(v, t2), s3 = __fadd_rn(v, t3);
        wd0 |= (u64)(s0 > 0.f) << c;  zd0 |= (u64)(s0 == 0.f) << c;
        wd1 |= (u64)(s1 > 0.f) << c;  zd1 |= (u64)(s1 == 0.f) << c;
        wd2 |= (u64)(s2 > 0.f) << c;  zd2 |= (u64)(s2 == 0.f) << c;
        wd3 |= (u64)(s3 > 0.f) << c;  zd3 |= (u64)(s3 == 0.f) << c;
    }
    ba1[(size_t)((0 * 64 + n) * 4 + g) * 900 + idx] = wd0;
    ba1[(size_t)((1 * 64 + n) * 4 + g) * 900 + idx] = wd1;
    ba1[(size_t)((2 * 64 + n) * 4 + g) * 900 + idx] = wd2;
    ba1[(size_t)((3 * 64 + n) * 4 + g) * 900 + idx] = wd3;
    bz1[(size_t)((0 * 64 + n) * 4 + g) * 900 + idx] = zd0;
    bz1[(size_t)((1 * 64 + n) * 4 + g) * 900 + idx] = zd1;
    bz1[(size_t)((2 * 64 + n) * 4 + g) * 900 + idx] = zd2;
    bz1[(size_t)((3 * 64 + n) * 4 + g) * 900 + idx] = zd3;
    if (zd0 | zd1 | zd2 | zd3) atomicOr((u32*)(ws + OFF_FLG1) + (n * 4 + g), 1u);
}

// ---------------- K4: layer-1 binary group-conv + BN + sum + identity + clip ----------------
// LDS-staged weights + chunked identity prefetch. Math/order identical to r3.
__global__ __launch_bounds__(256, 4) void k_conv1(const float* __restrict__ x, float* __restrict__ out,
                                                  char* __restrict__ ws) {
    int g = blockIdx.x / 196, bb = blockIdx.x % 196;
    int fp = bb * 256 + threadIdx.x;      // 0..50175 = n*784+pos
    int n = fp / 784, pos = fp - n * 784;
    int h = pos / 28, w = pos - h * 28;
    int rt = (h == 0) ? 0 : ((h == 27) ? 2 : 1);
    int ct = (w == 0) ? 0 : ((w == 27) ? 2 : 1);
    int pat = rt * 3 + ct;
    int pb = (h + 1) * 30 + (w + 1);

    __shared__ u64   wsm[2304];   // 64 oc x 36 words, 18432 B
    __shared__ float c1s[2304];   // 9216 B
    {
        const u64* wsrc = (const u64*)(ws + OFF_W1P) + (size_t)g * 2304;
        const float* C1 = (const float*)(ws + OFF_C1) + g * 2304;
        for (int k = threadIdx.x; k < 2304; k += 256) { wsm[k] = wsrc[k]; c1s[k] = C1[k]; }
    }
    const u64* ba1 = (const u64*)(ws + OFF_BA1);
    u64 aw[4][9];
#pragma unroll
    for (int i = 0; i < 4; i++) {
        const u64* bp = ba1 + (size_t)((i * 64 + n) * 4 + g) * 900 + pb;
#pragma unroll
        for (int t = 0; t < 9; t++) { int dh = t / 3 - 1, dw = t % 3 - 1; aw[i][t] = bp[dh * 30 + dw]; }
    }
    u32 zflag = ((const u32*)(ws + OFF_FLG1))[n * 4 + g];
    __syncthreads();

    const float* A1 = (const float*)(ws + OFF_A1) + g * 256;
    const float* S1 = (const float*)(ws + OFF_S1) + g * 256;
    const float* xb = x + (size_t)(n * 256 + g * 64) * 784 + pos;
    float* ob = out + (size_t)(n * 256 + g * 64) * 784 + pos;
    u64 bits = 0, zbits = 0;
    if (!zflag) {
        // fast path: no exact-zero activations anywhere in this (n,g)
        for (int cc = 0; cc < 8; cc++) {
            float id[8];
#pragma unroll
            for (int j = 0; j < 8; j++) id[j] = xb[(size_t)(cc * 8 + j) * 784];
#pragma unroll
            for (int j = 0; j < 8; j++) {
                int oc = cc * 8 + j;
                const u64* wp = wsm + oc * 36;
                u32 D[4];
#pragma unroll
                for (int i = 0; i < 4; i++) {
                    u32 d = 0;
#pragma unroll
                    for (int t = 0; t < 9; t++) d += (u32)__popcll(aw[i][t] ^ wp[i * 9 + t]);
                    D[i] = d;
                }
                float acc = 0.f;
#pragma unroll
                for (int i = 0; i < 4; i++) {
                    float cf = c1s[(oc * 4 + i) * 9 + pat];
                    float conv = __fmaf_rn(-2.f, (float)D[i], cf);          // exact small integer
                    float yi = __fadd_rn(__fmul_rn(conv, A1[oc * 4 + i]), S1[oc * 4 + i]);
                    acc = (i == 0) ? yi : __fadd_rn(acc, yi);               // ref's sum order
                }
                float o = __fadd_rn(acc, id[j]);
                o = fminf(fmaxf(o, -1.f), 1.f);
                bits  |= (u64)(o > 0.f) << oc;
                zbits |= (u64)(o == 0.f) << oc;
                ob[(size_t)oc * 784] = o;
            }
        }
    } else {
        // slow path: sign(0)=0 correction, Z re-read from global to keep VGPRs low
        const u64* bz1 = (const u64*)(ws + OFF_BZ1);
        for (int oc = 0; oc < 64; oc++) {
            const u64* wp = wsm + oc * 36;
            float acc = 0.f;
#pragma unroll
            for (int i = 0; i < 4; i++) {
                const u64* zp = bz1 + (size_t)((i * 64 + n) * 4 + g) * 900 + pb;
                u32 d = 0; int cz = 0;
#pragma unroll
                for (int t = 0; t < 9; t++) {
                    int dh = t / 3 - 1, dw = t % 3 - 1;
                    u64 zt = zp[dh * 30 + dw];
                    d += (u32)__popcll(aw[i][t] ^ wp[i * 9 + t]);
                    cz += 2 * (int)__popcll(zt & wp[i * 9 + t]) - (int)__popcll(zt);
                }
                float cf = c1s[(oc * 4 + i) * 9 + pat];
                float conv = __fadd_rn(__fmaf_rn(-2.f, (float)d, cf), (float)cz);  // exact ints
                float yi = __fadd_rn(__fmul_rn(conv, A1[oc * 4 + i]), S1[oc * 4 + i]);
                acc = (i == 0) ? yi : __fadd_rn(acc, yi);
            }
            float o = __fadd_rn(acc, xb[(size_t)oc * 784]);
            o = fminf(fmaxf(o, -1.f), 1.f);
            bits  |= (u64)(o > 0.f) << oc;
            zbits |= (u64)(o == 0.f) << oc;
            ob[(size_t)oc * 784] = o;
        }
    }
    ((u64*)(ws + OFF_BA2))[(size_t)(n * 4 + g) * 900 + pb] = bits;
    ((u64*)(ws + OFF_BZ2))[(size_t)(n * 4 + g) * 900 + pb] = zbits;
    if (zbits) atomicOr((u32*)(ws + OFF_FLG2) + n, 1u);
}

// ---------------- K5: layer-2 binary dense conv + BN + identity + clip ----------------
__global__ __launch_bounds__(256, 4) void k_conv2(float* __restrict__ out, char* __restrict__ ws) {
    int oq = blockIdx.x / 196, bb = blockIdx.x % 196;
    int fp = bb * 256 + threadIdx.x;
    int n = fp / 784, pos = fp - n * 784;
    int h = pos / 28, w = pos - h * 28;
    int rt = (h == 0) ? 0 : ((h == 27) ? 2 : 1);
    int ct = (w == 0) ? 0 : ((w == 27) ? 2 : 1);
    int pat = rt * 3 + ct;
    int pb = (h + 1) * 30 + (w + 1);

    __shared__ u64   wsm[2304];   // 64 oc x 36 words ([t*4+icw] per oc), 18432 B
    __shared__ float c2s[576];
    {
        const u64* wsrc = (const u64*)(ws + OFF_W2P) + (size_t)oq * 2304;
        for (int k = threadIdx.x; k < 2304; k += 256) wsm[k] = wsrc[k];
        const float* C2 = (const float*)(ws + OFF_C2) + oq * 576;
        for (int k = threadIdx.x; k < 576; k += 256) c2s[k] = C2[k];
    }
    const u64* ba2 = (const u64*)(ws + OFF_BA2);
    u64 aw[4][9];
#pragma unroll
    for (int icw = 0; icw < 4; icw++) {
        const u64* bp = ba2 + (size_t)(n * 4 + icw) * 900 + pb;
#pragma unroll
        for (int t = 0; t < 9; t++) { int dh = t / 3 - 1, dw = t % 3 - 1; aw[icw][t] = bp[dh * 30 + dw]; }
    }
    u32 zflag = ((const u32*)(ws + OFF_FLG2))[n];
    __syncthreads();

    const float* A2 = (const float*)(ws + OFF_A2) + oq * 64;
    const float* S2 = (const float*)(ws + OFF_S2) + oq * 64;
    float* ob = out + ((size_t)n * 256 + oq * 64) * 784 + pos;
    if (!zflag) {
        for (int cc = 0; cc < 8; cc++) {
            float id[8];
#pragma unroll
            for (int j = 0; j < 8; j++) id[j] = ob[(size_t)(cc * 8 + j) * 784];
#pragma unroll
            for (int j = 0; j < 8; j++) {
                int oc = cc * 8 + j;
                const u64* wp = wsm + oc * 36;                 // [t*4+icw]
                u32 dp0 = 0, dp1 = 0, dp2 = 0, dp3 = 0;
#pragma unroll
                for (int t = 0; t < 9; t++) {
                    dp0 += (u32)__popcll(aw[0][t] ^ wp[t * 4 + 0]);
                    dp1 += (u32)__popcll(aw[1][t] ^ wp[t * 4 + 1]);
                    dp2 += (u32)__popcll(aw[2][t] ^ wp[t * 4 + 2]);
                    dp3 += (u32)__popcll(aw[3][t] ^ wp[t * 4 + 3]);
                }
                u32 d = (dp0 + dp1) + (dp2 + dp3);
                float cf = c2s[oc * 9 + pat];
                float conv = __fmaf_rn(-2.f, (float)d, cf);      // exact small integer
                float y = __fadd_rn(__fmul_rn(conv, A2[oc]), S2[oc]);
                float o = __fadd_rn(y, id[j]);
                o = fminf(fmaxf(o, -1.f), 1.f);
                ob[(size_t)oc * 784] = o;
            }
        }
    } else {
        const u64* bz2 = (const u64*)(ws + OFF_BZ2);
        for (int oc = 0; oc < 64; oc++) {
            const u64* wp = wsm + oc * 36;
            u32 d = 0; int cz = 0;
#pragma unroll
            for (int icw = 0; icw < 4; icw++) {
                const u64* zp = bz2 + (size_t)(n * 4 + icw) * 900 + pb;
#pragma unroll
                for (int t = 0; t < 9; t++) {
                    int dh = t / 3 - 1, dw = t % 3 - 1;
                    u64 zt = zp[dh * 30 + dw];
                    d += (u32)__popcll(aw[icw][t] ^ wp[t * 4 + icw]);
                    cz += 2 * (int)__popcll(zt & wp[t * 4 + icw]) - (int)__popcll(zt);
                }
            }
            float cf = c2s[oc * 9 + pat];
            float conv = __fadd_rn(__fmaf_rn(-2.f, (float)d, cf), (float)cz);  // exact ints
            float y = __fadd_rn(__fmul_rn(conv, A2[oc]), S2[oc]);
            float idf = ob[(size_t)oc * 784];
            float o = __fadd_rn(y, idf);
            o = fminf(fmaxf(o, -1.f), 1.f);
            ob[(size_t)oc * 784] = o;
        }
    }
}

extern "C" void kernel_launch(void* const* d_in, const int* in_sizes, int n_in,
                              void* d_out, int out_size, void* d_ws, size_t ws_size,
                              hipStream_t stream) {
    const float* x  = (const float*)d_in[0];
    const float* w1 = (const float*)d_in[1];
    const float* g1 = (const float*)d_in[2];
    const float* b1 = (const float*)d_in[3];
    const float* m1 = (const float*)d_in[4];
    const float* v1 = (const float*)d_in[5];
    const float* w2 = (const float*)d_in[6];
    const float* g2 = (const float*)d_in[7];
    const float* b2 = (const float*)d_in[8];
    const float* m2 = (const float*)d_in[9];
    const float* v2 = (const float*)d_in[10];
    float* out = (float*)d_out;
    char* ws = (char*)d_ws;

    hipMemsetAsync(ws, 0, 2048, stream);   // xmax + zero-flags
    k_absmax<<<512, 256, 0, stream>>>((const float4*)x, (u32*)(ws + OFF_XMAX), NTOT / 4);
    k_prep1<<<256, 256, 0, stream>>>(w1, g1, b1, m1, v1, ws);
    k_prep2<<<64, 256, 0, stream>>>(w2, g2, b2, m2, v2, ws);
    k_pack<<<900, 256, 0, stream>>>(x, ws);
    k_conv1<<<784, 256, 0, stream>>>(x, out, ws);
    k_conv2<<<784, 256, 0, stream>>>(out, ws);
}

// Round 5
// 461.590 us; speedup vs baseline: 1.4467x; 1.4467x over previous
//
#include <hip/hip_runtime.h>
#include <stdint.h>

typedef uint32_t u32; typedef uint64_t u64; typedef unsigned short u16;

// Problem geometry
#define NB   64
#define NC   256
#define NG   4
#define HW   784      // 28*28
#define PHW  900      // 30*30 padded
#define NTOT 12845056 // 64*256*784

// Workspace layout (bytes); total footprint = 18,637,824 B
#define OFF_XMAX 0
#define OFF_FLG1 64                       // 256 u32: zero-flag per n*4+g (layer-1 acts)
#define OFF_FLG2 1088                     // 64 u32: zero-flag per n (layer-2 acts)
#define OFF_W1P  2048                     // [oc(256)][i(4)][tap(9)] u64 = 73728
#define OFF_W2P  75776                    // [oc(256)][tap(9)][icw(4)] u64 = 73728
#define OFF_A1   149504                   // [oc*4+i] f32
#define OFF_S1   153600
#define OFF_A2   157696                   // [oc] f32
#define OFF_S2   158720
#define OFF_C1   159744                   // [(oc*4+i)*9+pat] f32 = 36864
#define OFF_C2   196608                   // [oc*9+pat] f32 = 9216
#define OFF_BA1  205824                   // [i(4)][n(64)][g(4)][900] u64 = 7372800
#define OFF_BZ1  7578624                  // zero-masks, same layout as BA1
#define OFF_BA2  14951424                 // [n(64)][icw(4)][900] u64 = 1843200
#define OFF_BZ2  16794624                 // zero-masks, same layout as BA2

__device__ inline double wredsumd(double v) {
#pragma unroll
    for (int off = 32; off; off >>= 1) v += __shfl_xor(v, off);
    return v;
}

// ---------------- K0: max|x| ----------------
__global__ __launch_bounds__(256) void k_absmax(const float4* __restrict__ x, u32* __restrict__ xmax, int n4) {
    u32 m = 0;
    int idx = blockIdx.x * blockDim.x + threadIdx.x;
    int stride = gridDim.x * blockDim.x;
    for (int i = idx; i < n4; i += stride) {
        float4 v = x[i];
        m = max(m, __float_as_uint(v.x) & 0x7fffffffu);
        m = max(m, __float_as_uint(v.y) & 0x7fffffffu);
        m = max(m, __float_as_uint(v.z) & 0x7fffffffu);
        m = max(m, __float_as_uint(v.w) & 0x7fffffffu);
    }
#pragma unroll
    for (int off = 32; off; off >>= 1) {
        u32 o = (u32)__shfl_xor((int)m, off);
        m = max(m, o);
    }
    __shared__ u32 sm[4];
    int lane = threadIdx.x & 63, wid = threadIdx.x >> 6;
    if (lane == 0) sm[wid] = m;
    __syncthreads();
    if (threadIdx.x == 0) {
        u32 mm = max(max(sm[0], sm[1]), max(sm[2], sm[3]));
        atomicMax(xmax, mm);
    }
}

// ---------------- K1: prep layer-1 weights (f64 stats) ----------------
__global__ __launch_bounds__(256) void k_prep1(const float* __restrict__ w1, const float* __restrict__ g1,
                                               const float* __restrict__ b1, const float* __restrict__ m1,
                                               const float* __restrict__ v1, char* __restrict__ ws) {
    int lane = threadIdx.x & 63, wid = threadIdx.x >> 6;
    int cc = blockIdx.x * 4 + wid;        // 0..1023
    int i = cc >> 8, oc = cc & 255;       // branch, global out-channel
    const float* wp = w1 + ((size_t)(i * 256 + oc) * 64 + lane) * 9;
    float v[9];
#pragma unroll
    for (int t = 0; t < 9; t++) v[t] = wp[t];
    double s = 0.0;
#pragma unroll
    for (int t = 0; t < 9; t++) s += (double)v[t];
    s = wredsumd(s);
    double mean = s / 576.0;
    double ssq = 0.0, sab = 0.0;
#pragma unroll
    for (int t = 0; t < 9; t++) { double d = (double)v[t] - mean; ssq += d * d; sab += fabs(d); }
    ssq = wredsumd(ssq); sab = wredsumd(sab);
    double stdv = sqrt(ssq / 575.0);
    double meanabs = sab / 576.0 / stdv;
    float scale = (float)exp2(rint(log2(meanabs)));   // exact power of 2
    int bi = i * 256 + oc;
    float inv = __fdiv_rn(g1[bi], __fsqrt_rn(__fadd_rn(v1[bi], 1e-5f)));
    float A = __fmul_rn(scale, inv);      // exact: scale is a power of 2
    float S = __fsub_rn(b1[bi], __fmul_rn(m1[bi], inv));

    u64* w1p = (u64*)(ws + OFF_W1P);
    int c[9]; u64 keep = 0;
#pragma unroll
    for (int t = 0; t < 9; t++) {
        u64 bal = __ballot((double)v[t] > mean);
        c[t] = 64 - 2 * (int)__popcll(bal);   // = -sum of weight signs at tap t
        if (lane == t) keep = bal;
    }
    if (lane < 9) w1p[(size_t)(oc * 4 + i) * 9 + lane] = keep;
    if (lane == 0) {
        ((float*)(ws + OFF_A1))[oc * 4 + i] = A;
        ((float*)(ws + OFF_S1))[oc * 4 + i] = S;
        float* C1 = (float*)(ws + OFF_C1);
#pragma unroll
        for (int pat = 0; pat < 9; pat++) {
            int rt = pat / 3, ct = pat % 3, corr = 0;
#pragma unroll
            for (int t = 0; t < 9; t++) {
                int dh = t / 3 - 1, dw = t % 3 - 1;
                bool inval = (rt == 0 && dh < 0) || (rt == 2 && dh > 0) || (ct == 0 && dw < 0) || (ct == 2 && dw > 0);
                if (inval) corr += c[t];
            }
            C1[(oc * 4 + i) * 9 + pat] = (float)(576 - corr);
        }
    }
}

// ---------------- K2: prep layer-2 weights (f64 stats) ----------------
__global__ __launch_bounds__(256) void k_prep2(const float* __restrict__ w2, const float* __restrict__ g2,
                                               const float* __restrict__ b2, const float* __restrict__ m2,
                                               const float* __restrict__ v2, char* __restrict__ ws) {
    int lane = threadIdx.x & 63, wid = threadIdx.x >> 6;
    int oc = blockIdx.x * 4 + wid;        // 0..255
    float v[36];
#pragma unroll
    for (int icw = 0; icw < 4; icw++)
#pragma unroll
        for (int t = 0; t < 9; t++)
            v[icw * 9 + t] = w2[(size_t)(oc * 256 + icw * 64 + lane) * 9 + t];
    double s = 0.0;
#pragma unroll
    for (int k = 0; k < 36; k++) s += (double)v[k];
    s = wredsumd(s);
    double mean = s / 2304.0;
    double ssq = 0.0, sab = 0.0;
#pragma unroll
    for (int k = 0; k < 36; k++) { double d = (double)v[k] - mean; ssq += d * d; sab += fabs(d); }
    ssq = wredsumd(ssq); sab = wredsumd(sab);
    double stdv = sqrt(ssq / 2303.0);
    double meanabs = sab / 2304.0 / stdv;
    float scale = (float)exp2(rint(log2(meanabs)));
    float inv = __fdiv_rn(g2[oc], __fsqrt_rn(__fadd_rn(v2[oc], 1e-5f)));
    float A = __fmul_rn(scale, inv);
    float S = __fsub_rn(b2[oc], __fmul_rn(m2[oc], inv));

    u64* w2p = (u64*)(ws + OFF_W2P);
    int c2[9] = {0,0,0,0,0,0,0,0,0};
    u64 keep = 0;
#pragma unroll
    for (int icw = 0; icw < 4; icw++)
#pragma unroll
        for (int t = 0; t < 9; t++) {
            u64 bal = __ballot((double)v[icw * 9 + t] > mean);
            c2[t] += 64 - 2 * (int)__popcll(bal);
            if (lane == t * 4 + icw) keep = bal;
        }
    if (lane < 36) w2p[(size_t)oc * 36 + lane] = keep;
    if (lane == 0) {
        ((float*)(ws + OFF_A2))[oc] = A;
        ((float*)(ws + OFF_S2))[oc] = S;
        float* C2 = (float*)(ws + OFF_C2);
#pragma unroll
        for (int pat = 0; pat < 9; pat++) {
            int rt = pat / 3, ct = pat % 3, corr = 0;
#pragma unroll
            for (int t = 0; t < 9; t++) {
                int dh = t / 3 - 1, dw = t % 3 - 1;
                bool inval = (rt == 0 && dh < 0) || (rt == 2 && dh > 0) || (ct == 0 && dw < 0) || (ct == 2 && dw > 0);
                if (inval) corr += c2[t];
            }
            C2[oc * 9 + pat] = (float)(2304 - corr);
        }
    }
}

// ---------------- K3: pack 4 shifted sign-activations + zero masks (zero halo) ----------------
__global__ __launch_bounds__(256) void k_pack(const float* __restrict__ x, char* __restrict__ ws) {
    int g = blockIdx.x / 225, bb = blockIdx.x % 225;
    int fp = bb * 256 + threadIdx.x;      // 0..57599 = n*900+idx
    int n = fp / 900, idx = fp - n * 900;
    int ph = idx / 30, pw = idx - ph * 30;
    u64* ba1 = (u64*)(ws + OFF_BA1);
    u64* bz1 = (u64*)(ws + OFF_BZ1);
    bool halo = (ph == 0) | (ph == 29) | (pw == 0) | (pw == 29);
    if (halo) {
#pragma unroll
        for (int i = 0; i < 4; i++) {
            size_t o = (size_t)((i * 64 + n) * 4 + g) * 900 + idx;
            ba1[o] = 0; bz1[o] = 0;
        }
        ((u64*)(ws + OFF_BA2))[(size_t)(n * 4 + g) * 900 + idx] = 0;
        ((u64*)(ws + OFF_BZ2))[(size_t)(n * 4 + g) * 900 + idx] = 0;
        return;
    }
    float xmax = *(const float*)(ws + OFF_XMAX);    // bits of max|x| == value
    float t0 = __fmul_rn(-0.6f, xmax), t1 = __fmul_rn(-0.2f, xmax);
    float t2 = __fmul_rn(0.2f, xmax), t3 = __fmul_rn(0.6f, xmax);
    int h = ph - 1, w = pw - 1;
    const float* xb = x + (size_t)(n * 256 + g * 64) * 784 + (h * 28 + w);
    u64 wd0 = 0, wd1 = 0, wd2 = 0, wd3 = 0;
    u64 zd0 = 0, zd1 = 0, zd2 = 0, zd3 = 0;
#pragma unroll 8
    for (int c = 0; c < 64; c++) {
        float v = xb[(size_t)c * 784];
        float s0 = __fadd_rn(v, t0), s1 = __fadd_rn(v, t1);
        float s2 = __fadd_rn(v, t2), s3 = __fadd_rn(v, t3);
        wd0 |= (u64)(s0 > 0.f) << c;  zd0 |= (u64)(s0 == 0.f) << c;
        wd1 |= (u64)(s1 > 0.f) << c;  zd1 |= (u64)(s1 == 0.f) << c;
        wd2 |= (u64)(s2 > 0.f) << c;  zd2 |= (u64)(s2 == 0.f) << c;
        wd3 |= (u64)(s3 > 0.f) << c;  zd3 |= (u64)(s3 == 0.f) << c;
    }
    ba1[(size_t)((0 * 64 + n) * 4 + g) * 900 + idx] = wd0;
    ba1[(size_t)((1 * 64 + n) * 4 + g) * 900 + idx] = wd1;
    ba1[(size_t)((2 * 64 + n) * 4 + g) * 900 + idx] = wd2;
    ba1[(size_t)((3 * 64 + n) * 4 + g) * 900 + idx] = wd3;
    bz1[(size_t)((0 * 64 + n) * 4 + g) * 900 + idx] = zd0;
    bz1[(size_t)((1 * 64 + n) * 4 + g) * 900 + idx] = zd1;
    bz1[(size_t)((2 * 64 + n) * 4 + g) * 900 + idx] = zd2;
    bz1[(size_t)((3 * 64 + n) * 4 + g) * 900 + idx] = zd3;
    if (zd0 | zd1 | zd2 | zd3) atomicOr((u32*)(ws + OFF_FLG1) + (n * 4 + g), 1u);
}

// ---------------- K4: layer-1 binary group-conv + BN + sum + identity + clip ----------------
// LDS-staged weights + chunked identity prefetch. NO min-waves bound: aw[4][9]
// needs 72 VGPRs live; (256,4) forced 64-VGPR budget -> scratch spill -> 5x HBM traffic (r4).
__global__ __launch_bounds__(256) void k_conv1(const float* __restrict__ x, float* __restrict__ out,
                                               char* __restrict__ ws) {
    int g = blockIdx.x / 196, bb = blockIdx.x % 196;
    int fp = bb * 256 + threadIdx.x;      // 0..50175 = n*784+pos
    int n = fp / 784, pos = fp - n * 784;
    int h = pos / 28, w = pos - h * 28;
    int rt = (h == 0) ? 0 : ((h == 27) ? 2 : 1);
    int ct = (w == 0) ? 0 : ((w == 27) ? 2 : 1);
    int pat = rt * 3 + ct;
    int pb = (h + 1) * 30 + (w + 1);

    __shared__ u64   wsm[2304];   // 64 oc x 36 words, 18432 B
    __shared__ float c1s[2304];   // 9216 B
    {
        const u64* wsrc = (const u64*)(ws + OFF_W1P) + (size_t)g * 2304;
        const float* C1 = (const float*)(ws + OFF_C1) + g * 2304;
        for (int k = threadIdx.x; k < 2304; k += 256) { wsm[k] = wsrc[k]; c1s[k] = C1[k]; }
    }
    const u64* ba1 = (const u64*)(ws + OFF_BA1);
    u64 aw[4][9];
#pragma unroll
    for (int i = 0; i < 4; i++) {
        const u64* bp = ba1 + (size_t)((i * 64 + n) * 4 + g) * 900 + pb;
#pragma unroll
        for (int t = 0; t < 9; t++) { int dh = t / 3 - 1, dw = t % 3 - 1; aw[i][t] = bp[dh * 30 + dw]; }
    }
    u32 zflag = ((const u32*)(ws + OFF_FLG1))[n * 4 + g];
    __syncthreads();

    const float* A1 = (const float*)(ws + OFF_A1) + g * 256;
    const float* S1 = (const float*)(ws + OFF_S1) + g * 256;
    const float* xb = x + (size_t)(n * 256 + g * 64) * 784 + pos;
    float* ob = out + (size_t)(n * 256 + g * 64) * 784 + pos;
    u64 bits = 0, zbits = 0;
    if (!zflag) {
        // fast path: no exact-zero activations anywhere in this (n,g)
        for (int cc = 0; cc < 8; cc++) {
            float id[8];
#pragma unroll
            for (int j = 0; j < 8; j++) id[j] = xb[(size_t)(cc * 8 + j) * 784];
#pragma unroll
            for (int j = 0; j < 8; j++) {
                int oc = cc * 8 + j;
                const u64* wp = wsm + oc * 36;
                u32 D[4];
#pragma unroll
                for (int i = 0; i < 4; i++) {
                    u32 d = 0;
#pragma unroll
                    for (int t = 0; t < 9; t++) d += (u32)__popcll(aw[i][t] ^ wp[i * 9 + t]);
                    D[i] = d;
                }
                float acc = 0.f;
#pragma unroll
                for (int i = 0; i < 4; i++) {
                    float cf = c1s[(oc * 4 + i) * 9 + pat];
                    float conv = __fmaf_rn(-2.f, (float)D[i], cf);          // exact small integer
                    float yi = __fadd_rn(__fmul_rn(conv, A1[oc * 4 + i]), S1[oc * 4 + i]);
                    acc = (i == 0) ? yi : __fadd_rn(acc, yi);               // ref's sum order
                }
                float o = __fadd_rn(acc, id[j]);
                o = fminf(fmaxf(o, -1.f), 1.f);
                bits  |= (u64)(o > 0.f) << oc;
                zbits |= (u64)(o == 0.f) << oc;
                ob[(size_t)oc * 784] = o;
            }
        }
    } else {
        // slow path: sign(0)=0 correction, Z re-read from global to keep VGPRs low
        const u64* bz1 = (const u64*)(ws + OFF_BZ1);
        for (int oc = 0; oc < 64; oc++) {
            const u64* wp = wsm + oc * 36;
            float acc = 0.f;
#pragma unroll
            for (int i = 0; i < 4; i++) {
                const u64* zp = bz1 + (size_t)((i * 64 + n) * 4 + g) * 900 + pb;
                u32 d = 0; int cz = 0;
#pragma unroll
                for (int t = 0; t < 9; t++) {
                    int dh = t / 3 - 1, dw = t % 3 - 1;
                    u64 zt = zp[dh * 30 + dw];
                    d += (u32)__popcll(aw[i][t] ^ wp[i * 9 + t]);
                    cz += 2 * (int)__popcll(zt & wp[i * 9 + t]) - (int)__popcll(zt);
                }
                float cf = c1s[(oc * 4 + i) * 9 + pat];
                float conv = __fadd_rn(__fmaf_rn(-2.f, (float)d, cf), (float)cz);  // exact ints
                float yi = __fadd_rn(__fmul_rn(conv, A1[oc * 4 + i]), S1[oc * 4 + i]);
                acc = (i == 0) ? yi : __fadd_rn(acc, yi);
            }
            float o = __fadd_rn(acc, xb[(size_t)oc * 784]);
            o = fminf(fmaxf(o, -1.f), 1.f);
            bits  |= (u64)(o > 0.f) << oc;
            zbits |= (u64)(o == 0.f) << oc;
            ob[(size_t)oc * 784] = o;
        }
    }
    ((u64*)(ws + OFF_BA2))[(size_t)(n * 4 + g) * 900 + pb] = bits;
    ((u64*)(ws + OFF_BZ2))[(size_t)(n * 4 + g) * 900 + pb] = zbits;
    if (zbits) atomicOr((u32*)(ws + OFF_FLG2) + n, 1u);
}

// ---------------- K5: layer-2 binary dense conv + BN + identity + clip ----------------
__global__ __launch_bounds__(256) void k_conv2(float* __restrict__ out, char* __restrict__ ws) {
    int oq = blockIdx.x / 196, bb = blockIdx.x % 196;
    int fp = bb * 256 + threadIdx.x;
    int n = fp / 784, pos = fp - n * 784;
    int h = pos / 28, w = pos - h * 28;
    int rt = (h == 0) ? 0 : ((h == 27) ? 2 : 1);
    int ct = (w == 0) ? 0 : ((w == 27) ? 2 : 1);
    int pat = rt * 3 + ct;
    int pb = (h + 1) * 30 + (w + 1);

    __shared__ u64   wsm[2304];   // 64 oc x 36 words ([t*4+icw] per oc), 18432 B
    __shared__ float c2s[576];
    {
        const u64* wsrc = (const u64*)(ws + OFF_W2P) + (size_t)oq * 2304;
        for (int k = threadIdx.x; k < 2304; k += 256) wsm[k] = wsrc[k];
        const float* C2 = (const float*)(ws + OFF_C2) + oq * 576;
        for (int k = threadIdx.x; k < 576; k += 256) c2s[k] = C2[k];
    }
    const u64* ba2 = (const u64*)(ws + OFF_BA2);
    u64 aw[4][9];
#pragma unroll
    for (int icw = 0; icw < 4; icw++) {
        const u64* bp = ba2 + (size_t)(n * 4 + icw) * 900 + pb;
#pragma unroll
        for (int t = 0; t < 9; t++) { int dh = t / 3 - 1, dw = t % 3 - 1; aw[icw][t] = bp[dh * 30 + dw]; }
    }
    u32 zflag = ((const u32*)(ws + OFF_FLG2))[n];
    __syncthreads();

    const float* A2 = (const float*)(ws + OFF_A2) + oq * 64;
    const float* S2 = (const float*)(ws + OFF_S2) + oq * 64;
    float* ob = out + ((size_t)n * 256 + oq * 64) * 784 + pos;
    if (!zflag) {
        for (int cc = 0; cc < 8; cc++) {
            float id[8];
#pragma unroll
            for (int j = 0; j < 8; j++) id[j] = ob[(size_t)(cc * 8 + j) * 784];
#pragma unroll
            for (int j = 0; j < 8; j++) {
                int oc = cc * 8 + j;
                const u64* wp = wsm + oc * 36;                 // [t*4+icw]
                u32 dp0 = 0, dp1 = 0, dp2 = 0, dp3 = 0;
#pragma unroll
                for (int t = 0; t < 9; t++) {
                    dp0 += (u32)__popcll(aw[0][t] ^ wp[t * 4 + 0]);
                    dp1 += (u32)__popcll(aw[1][t] ^ wp[t * 4 + 1]);
                    dp2 += (u32)__popcll(aw[2][t] ^ wp[t * 4 + 2]);
                    dp3 += (u32)__popcll(aw[3][t] ^ wp[t * 4 + 3]);
                }
                u32 d = (dp0 + dp1) + (dp2 + dp3);
                float cf = c2s[oc * 9 + pat];
                float conv = __fmaf_rn(-2.f, (float)d, cf);      // exact small integer
                float y = __fadd_rn(__fmul_rn(conv, A2[oc]), S2[oc]);
                float o = __fadd_rn(y, id[j]);
                o = fminf(fmaxf(o, -1.f), 1.f);
                ob[(size_t)oc * 784] = o;
            }
        }
    } else {
        const u64* bz2 = (const u64*)(ws + OFF_BZ2);
        for (int oc = 0; oc < 64; oc++) {
            const u64* wp = wsm + oc * 36;
            u32 d = 0; int cz = 0;
#pragma unroll
            for (int icw = 0; icw < 4; icw++) {
                const u64* zp = bz2 + (size_t)(n * 4 + icw) * 900 + pb;
#pragma unroll
                for (int t = 0; t < 9; t++) {
                    int dh = t / 3 - 1, dw = t % 3 - 1;
                    u64 zt = zp[dh * 30 + dw];
                    d += (u32)__popcll(aw[icw][t] ^ wp[t * 4 + icw]);
                    cz += 2 * (int)__popcll(zt & wp[t * 4 + icw]) - (int)__popcll(zt);
                }
            }
            float cf = c2s[oc * 9 + pat];
            float conv = __fadd_rn(__fmaf_rn(-2.f, (float)d, cf), (float)cz);  // exact ints
            float y = __fadd_rn(__fmul_rn(conv, A2[oc]), S2[oc]);
            float idf = ob[(size_t)oc * 784];
            float o = __fadd_rn(y, idf);
            o = fminf(fmaxf(o, -1.f), 1.f);
            ob[(size_t)oc * 784] = o;
        }
    }
}

extern "C" void kernel_launch(void* const* d_in, const int* in_sizes, int n_in,
                              void* d_out, int out_size, void* d_ws, size_t ws_size,
                              hipStream_t stream) {
    const float* x  = (const float*)d_in[0];
    const float* w1 = (const float*)d_in[1];
    const float* g1 = (const float*)d_in[2];
    const float* b1 = (const float*)d_in[3];
    const float* m1 = (const float*)d_in[4];
    const float* v1 = (const float*)d_in[5];
    const float* w2 = (const float*)d_in[6];
    const float* g2 = (const float*)d_in[7];
    const float* b2 = (const float*)d_in[8];
    const float* m2 = (const float*)d_in[9];
    const float* v2 = (const float*)d_in[10];
    float* out = (float*)d_out;
    char* ws = (char*)d_ws;

    hipMemsetAsync(ws, 0, 2048, stream);   // xmax + zero-flags
    k_absmax<<<512, 256, 0, stream>>>((const float4*)x, (u32*)(ws + OFF_XMAX), NTOT / 4);
    k_prep1<<<256, 256, 0, stream>>>(w1, g1, b1, m1, v1, ws);
    k_prep2<<<64, 256, 0, stream>>>(w2, g2, b2, m2, v2, ws);
    k_pack<<<900, 256, 0, stream>>>(x, ws);
    k_conv1<<<784, 256, 0, stream>>>(x, out, ws);
    k_conv2<<<784, 256, 0, stream>>>(out, ws);
}

// Round 6
// 322.421 us; speedup vs baseline: 2.0711x; 1.4316x over previous
//
#include <hip/hip_runtime.h>
#include <stdint.h>

typedef uint32_t u32; typedef uint64_t u64; typedef unsigned short u16;

// Problem geometry
#define NB   64
#define NC   256
#define NG   4
#define HW   784      // 28*28
#define PHW  900      // 30*30 padded
#define NTOT 12845056 // 64*256*784

// Workspace layout (bytes); total footprint = 18,637,824 B
#define OFF_XMAX 0
#define OFF_FLG1 64                       // 256 u32: zero-flag per n*4+g (layer-1 acts)
#define OFF_FLG2 1088                     // 64 u32: zero-flag per n (layer-2 acts)
#define OFF_W1P  2048                     // [oc(256)][i(4)][tap(9)] u64 = 73728
#define OFF_W2P  75776                    // [oc(256)][tap(9)][icw(4)] u64 = 73728
#define OFF_A1   149504                   // [oc*4+i] f32
#define OFF_S1   153600
#define OFF_A2   157696                   // [oc] f32
#define OFF_S2   158720
#define OFF_C1   159744                   // [(oc*4+i)*9+pat] f32 = 36864
#define OFF_C2   196608                   // [oc*9+pat] f32 = 9216
#define OFF_BA1  205824                   // [i(4)][n(64)][g(4)][900] u64 = 7372800
#define OFF_BZ1  7578624                  // zero-masks, same layout as BA1
#define OFF_BA2  14951424                 // [n(64)][icw(4)][900] u64 = 1843200
#define OFF_BZ2  16794624                 // zero-masks, same layout as BA2

__device__ inline double wredsumd(double v) {
#pragma unroll
    for (int off = 32; off; off >>= 1) v += __shfl_xor(v, off);
    return v;
}

// ---------------- K0: max|x| ----------------
__global__ __launch_bounds__(256) void k_absmax(const float4* __restrict__ x, u32* __restrict__ xmax, int n4) {
    u32 m = 0;
    int idx = blockIdx.x * blockDim.x + threadIdx.x;
    int stride = gridDim.x * blockDim.x;
    for (int i = idx; i < n4; i += stride) {
        float4 v = x[i];
        m = max(m, __float_as_uint(v.x) & 0x7fffffffu);
        m = max(m, __float_as_uint(v.y) & 0x7fffffffu);
        m = max(m, __float_as_uint(v.z) & 0x7fffffffu);
        m = max(m, __float_as_uint(v.w) & 0x7fffffffu);
    }
#pragma unroll
    for (int off = 32; off; off >>= 1) {
        u32 o = (u32)__shfl_xor((int)m, off);
        m = max(m, o);
    }
    __shared__ u32 sm[4];
    int lane = threadIdx.x & 63, wid = threadIdx.x >> 6;
    if (lane == 0) sm[wid] = m;
    __syncthreads();
    if (threadIdx.x == 0) {
        u32 mm = max(max(sm[0], sm[1]), max(sm[2], sm[3]));
        atomicMax(xmax, mm);
    }
}

// ---------------- K1: prep layer-1 weights (f64 stats) ----------------
__global__ __launch_bounds__(256) void k_prep1(const float* __restrict__ w1, const float* __restrict__ g1,
                                               const float* __restrict__ b1, const float* __restrict__ m1,
                                               const float* __restrict__ v1, char* __restrict__ ws) {
    int lane = threadIdx.x & 63, wid = threadIdx.x >> 6;
    int cc = blockIdx.x * 4 + wid;        // 0..1023
    int i = cc >> 8, oc = cc & 255;       // branch, global out-channel
    const float* wp = w1 + ((size_t)(i * 256 + oc) * 64 + lane) * 9;
    float v[9];
#pragma unroll
    for (int t = 0; t < 9; t++) v[t] = wp[t];
    double s = 0.0;
#pragma unroll
    for (int t = 0; t < 9; t++) s += (double)v[t];
    s = wredsumd(s);
    double mean = s / 576.0;
    double ssq = 0.0, sab = 0.0;
#pragma unroll
    for (int t = 0; t < 9; t++) { double d = (double)v[t] - mean; ssq += d * d; sab += fabs(d); }
    ssq = wredsumd(ssq); sab = wredsumd(sab);
    double stdv = sqrt(ssq / 575.0);
    double meanabs = sab / 576.0 / stdv;
    float scale = (float)exp2(rint(log2(meanabs)));   // exact power of 2
    int bi = i * 256 + oc;
    float inv = __fdiv_rn(g1[bi], __fsqrt_rn(__fadd_rn(v1[bi], 1e-5f)));
    float A = __fmul_rn(scale, inv);      // exact: scale is a power of 2
    float S = __fsub_rn(b1[bi], __fmul_rn(m1[bi], inv));

    u64* w1p = (u64*)(ws + OFF_W1P);
    int c[9]; u64 keep = 0;
#pragma unroll
    for (int t = 0; t < 9; t++) {
        u64 bal = __ballot((double)v[t] > mean);
        c[t] = 64 - 2 * (int)__popcll(bal);   // = -sum of weight signs at tap t
        if (lane == t) keep = bal;
    }
    if (lane < 9) w1p[(size_t)(oc * 4 + i) * 9 + lane] = keep;
    if (lane == 0) {
        ((float*)(ws + OFF_A1))[oc * 4 + i] = A;
        ((float*)(ws + OFF_S1))[oc * 4 + i] = S;
        float* C1 = (float*)(ws + OFF_C1);
#pragma unroll
        for (int pat = 0; pat < 9; pat++) {
            int rt = pat / 3, ct = pat % 3, corr = 0;
#pragma unroll
            for (int t = 0; t < 9; t++) {
                int dh = t / 3 - 1, dw = t % 3 - 1;
                bool inval = (rt == 0 && dh < 0) || (rt == 2 && dh > 0) || (ct == 0 && dw < 0) || (ct == 2 && dw > 0);
                if (inval) corr += c[t];
            }
            C1[(oc * 4 + i) * 9 + pat] = (float)(576 - corr);
        }
    }
}

// ---------------- K2: prep layer-2 weights (f64 stats) ----------------
__global__ __launch_bounds__(256) void k_prep2(const float* __restrict__ w2, const float* __restrict__ g2,
                                               const float* __restrict__ b2, const float* __restrict__ m2,
                                               const float* __restrict__ v2, char* __restrict__ ws) {
    int lane = threadIdx.x & 63, wid = threadIdx.x >> 6;
    int oc = blockIdx.x * 4 + wid;        // 0..255
    float v[36];
#pragma unroll
    for (int icw = 0; icw < 4; icw++)
#pragma unroll
        for (int t = 0; t < 9; t++)
            v[icw * 9 + t] = w2[(size_t)(oc * 256 + icw * 64 + lane) * 9 + t];
    double s = 0.0;
#pragma unroll
    for (int k = 0; k < 36; k++) s += (double)v[k];
    s = wredsumd(s);
    double mean = s / 2304.0;
    double ssq = 0.0, sab = 0.0;
#pragma unroll
    for (int k = 0; k < 36; k++) { double d = (double)v[k] - mean; ssq += d * d; sab += fabs(d); }
    ssq = wredsumd(ssq); sab = wredsumd(sab);
    double stdv = sqrt(ssq / 2303.0);
    double meanabs = sab / 2304.0 / stdv;
    float scale = (float)exp2(rint(log2(meanabs)));
    float inv = __fdiv_rn(g2[oc], __fsqrt_rn(__fadd_rn(v2[oc], 1e-5f)));
    float A = __fmul_rn(scale, inv);
    float S = __fsub_rn(b2[oc], __fmul_rn(m2[oc], inv));

    u64* w2p = (u64*)(ws + OFF_W2P);
    int c2[9] = {0,0,0,0,0,0,0,0,0};
    u64 keep = 0;
#pragma unroll
    for (int icw = 0; icw < 4; icw++)
#pragma unroll
        for (int t = 0; t < 9; t++) {
            u64 bal = __ballot((double)v[icw * 9 + t] > mean);
            c2[t] += 64 - 2 * (int)__popcll(bal);
            if (lane == t * 4 + icw) keep = bal;
        }
    if (lane < 36) w2p[(size_t)oc * 36 + lane] = keep;
    if (lane == 0) {
        ((float*)(ws + OFF_A2))[oc] = A;
        ((float*)(ws + OFF_S2))[oc] = S;
        float* C2 = (float*)(ws + OFF_C2);
#pragma unroll
        for (int pat = 0; pat < 9; pat++) {
            int rt = pat / 3, ct = pat % 3, corr = 0;
#pragma unroll
            for (int t = 0; t < 9; t++) {
                int dh = t / 3 - 1, dw = t % 3 - 1;
                bool inval = (rt == 0 && dh < 0) || (rt == 2 && dh > 0) || (ct == 0 && dw < 0) || (ct == 2 && dw > 0);
                if (inval) corr += c2[t];
            }
            C2[oc * 9 + pat] = (float)(2304 - corr);
        }
    }
}

// ---------------- K3: pack 4 shifted sign-activations + zero masks (zero halo) ----------------
__global__ __launch_bounds__(256) void k_pack(const float* __restrict__ x, char* __restrict__ ws) {
    int g = blockIdx.x / 225, bb = blockIdx.x % 225;
    int fp = bb * 256 + threadIdx.x;      // 0..57599 = n*900+idx
    int n = fp / 900, idx = fp - n * 900;
    int ph = idx / 30, pw = idx - ph * 30;
    u64* ba1 = (u64*)(ws + OFF_BA1);
    u64* bz1 = (u64*)(ws + OFF_BZ1);
    bool halo = (ph == 0) | (ph == 29) | (pw == 0) | (pw == 29);
    if (halo) {
#pragma unroll
        for (int i = 0; i < 4; i++) {
            size_t o = (size_t)((i * 64 + n) * 4 + g) * 900 + idx;
            ba1[o] = 0; bz1[o] = 0;
        }
        ((u64*)(ws + OFF_BA2))[(size_t)(n * 4 + g) * 900 + idx] = 0;
        ((u64*)(ws + OFF_BZ2))[(size_t)(n * 4 + g) * 900 + idx] = 0;
        return;
    }
    float xmax = *(const float*)(ws + OFF_XMAX);    // bits of max|x| == value
    float t0 = __fmul_rn(-0.6f, xmax), t1 = __fmul_rn(-0.2f, xmax);
    float t2 = __fmul_rn(0.2f, xmax), t3 = __fmul_rn(0.6f, xmax);
    int h = ph - 1, w = pw - 1;
    const float* xb = x + (size_t)(n * 256 + g * 64) * 784 + (h * 28 + w);
    u64 wd0 = 0, wd1 = 0, wd2 = 0, wd3 = 0;
    u64 zd0 = 0, zd1 = 0, zd2 = 0, zd3 = 0;
#pragma unroll 8
    for (int c = 0; c < 64; c++) {
        float v = xb[(size_t)c * 784];
        float s0 = __fadd_rn(v, t0), s1 = __fadd_rn(v, t1);
        float s2 = __fadd_rn(v, t2), s3 = __fadd_rn(v, t3);
        wd0 |= (u64)(s0 > 0.f) << c;  zd0 |= (u64)(s0 == 0.f) << c;
        wd1 |= (u64)(s1 > 0.f) << c;  zd1 |= (u64)(s1 == 0.f) << c;
        wd2 |= (u64)(s2 > 0.f) << c;  zd2 |= (u64)(s2 == 0.f) << c;
        wd3 |= (u64)(s3 > 0.f) << c;  zd3 |= (u64)(s3 == 0.f) << c;
    }
    ba1[(size_t)((0 * 64 + n) * 4 + g) * 900 + idx] = wd0;
    ba1[(size_t)((1 * 64 + n) * 4 + g) * 900 + idx] = wd1;
    ba1[(size_t)((2 * 64 + n) * 4 + g) * 900 + idx] = wd2;
    ba1[(size_t)((3 * 64 + n) * 4 + g) * 900 + idx] = wd3;
    bz1[(size_t)((0 * 64 + n) * 4 + g) * 900 + idx] = zd0;
    bz1[(size_t)((1 * 64 + n) * 4 + g) * 900 + idx] = zd1;
    bz1[(size_t)((2 * 64 + n) * 4 + g) * 900 + idx] = zd2;
    bz1[(size_t)((3 * 64 + n) * 4 + g) * 900 + idx] = zd3;
    if (zd0 | zd1 | zd2 | zd3) atomicOr((u32*)(ws + OFF_FLG1) + (n * 4 + g), 1u);
}

// ---------------- K4: layer-1 binary group-conv, oc-split x4 for occupancy ----------------
// Each block: one (g, quarter q) x 256 positions; 16 output channels.
// Sign/zero bits written as u16 slices of the BA2/BZ2 u64 words (little-endian).
__global__ __launch_bounds__(256) void k_conv1(const float* __restrict__ x, float* __restrict__ out,
                                               char* __restrict__ ws) {
    int gq = blockIdx.x / 196, bb = blockIdx.x % 196;
    int g = gq >> 2, q = gq & 3;          // group, oc-quarter
    int fp = bb * 256 + threadIdx.x;      // 0..50175 = n*784+pos
    int n = fp / 784, pos = fp - n * 784;
    int h = pos / 28, w = pos - h * 28;
    int rt = (h == 0) ? 0 : ((h == 27) ? 2 : 1);
    int ct = (w == 0) ? 0 : ((w == 27) ? 2 : 1);
    int pat = rt * 3 + ct;
    int pb = (h + 1) * 30 + (w + 1);

    __shared__ u64   wsm[576];    // 16 oc x 36 words
    __shared__ float c1s[576];    // 16 oc x 4 i x 9 pat
    {
        const u64* wsrc = (const u64*)(ws + OFF_W1P) + (size_t)g * 2304 + q * 576;
        const float* C1 = (const float*)(ws + OFF_C1) + g * 2304 + q * 576;
        for (int k = threadIdx.x; k < 576; k += 256) { wsm[k] = wsrc[k]; c1s[k] = C1[k]; }
    }
    const u64* ba1 = (const u64*)(ws + OFF_BA1);
    u64 aw[4][9];
#pragma unroll
    for (int i = 0; i < 4; i++) {
        const u64* bp = ba1 + (size_t)((i * 64 + n) * 4 + g) * 900 + pb;
#pragma unroll
        for (int t = 0; t < 9; t++) { int dh = t / 3 - 1, dw = t % 3 - 1; aw[i][t] = bp[dh * 30 + dw]; }
    }
    u32 zflag = ((const u32*)(ws + OFF_FLG1))[n * 4 + g];
    __syncthreads();

    const float* A1 = (const float*)(ws + OFF_A1) + g * 256 + q * 64;   // [j*4+i]
    const float* S1 = (const float*)(ws + OFF_S1) + g * 256 + q * 64;
    const float* xb = x + (size_t)(n * 256 + g * 64 + q * 16) * 784 + pos;
    float* ob = out + (size_t)(n * 256 + g * 64 + q * 16) * 784 + pos;
    u32 bits = 0, zbits = 0;
    if (!zflag) {
        // fast path: no exact-zero activations anywhere in this (n,g)
        float id[16];
#pragma unroll
        for (int j = 0; j < 16; j++) id[j] = xb[(size_t)j * 784];
#pragma unroll
        for (int j = 0; j < 16; j++) {
            const u64* wp = wsm + j * 36;
            u32 D[4];
#pragma unroll
            for (int i = 0; i < 4; i++) {
                u32 d = 0;
#pragma unroll
                for (int t = 0; t < 9; t++) d += (u32)__popcll(aw[i][t] ^ wp[i * 9 + t]);
                D[i] = d;
            }
            float acc = 0.f;
#pragma unroll
            for (int i = 0; i < 4; i++) {
                float cf = c1s[(j * 4 + i) * 9 + pat];
                float conv = __fmaf_rn(-2.f, (float)D[i], cf);          // exact small integer
                float yi = __fadd_rn(__fmul_rn(conv, A1[j * 4 + i]), S1[j * 4 + i]);
                acc = (i == 0) ? yi : __fadd_rn(acc, yi);               // ref's sum order
            }
            float o = __fadd_rn(acc, id[j]);
            o = fminf(fmaxf(o, -1.f), 1.f);
            bits  |= (u32)(o > 0.f) << j;
            zbits |= (u32)(o == 0.f) << j;
            ob[(size_t)j * 784] = o;
        }
    } else {
        // slow path: sign(0)=0 correction, Z re-read from global to keep VGPRs low
        const u64* bz1 = (const u64*)(ws + OFF_BZ1);
        for (int j = 0; j < 16; j++) {
            const u64* wp = wsm + j * 36;
            float acc = 0.f;
#pragma unroll
            for (int i = 0; i < 4; i++) {
                const u64* zp = bz1 + (size_t)((i * 64 + n) * 4 + g) * 900 + pb;
                u32 d = 0; int cz = 0;
#pragma unroll
                for (int t = 0; t < 9; t++) {
                    int dh = t / 3 - 1, dw = t % 3 - 1;
                    u64 zt = zp[dh * 30 + dw];
                    d += (u32)__popcll(aw[i][t] ^ wp[i * 9 + t]);
                    cz += 2 * (int)__popcll(zt & wp[i * 9 + t]) - (int)__popcll(zt);
                }
                float cf = c1s[(j * 4 + i) * 9 + pat];
                float conv = __fadd_rn(__fmaf_rn(-2.f, (float)d, cf), (float)cz);  // exact ints
                float yi = __fadd_rn(__fmul_rn(conv, A1[j * 4 + i]), S1[j * 4 + i]);
                acc = (i == 0) ? yi : __fadd_rn(acc, yi);
            }
            float o = __fadd_rn(acc, xb[(size_t)j * 784]);
            o = fminf(fmaxf(o, -1.f), 1.f);
            bits  |= (u32)(o > 0.f) << j;
            zbits |= (u32)(o == 0.f) << j;
            ob[(size_t)j * 784] = o;
        }
    }
    size_t widx = (size_t)(n * 4 + g) * 900 + pb;
    ((u16*)(ws + OFF_BA2))[widx * 4 + q] = (u16)bits;    // bits [16q,16q+16) of the u64 word
    ((u16*)(ws + OFF_BZ2))[widx * 4 + q] = (u16)zbits;
    if (zbits) atomicOr((u32*)(ws + OFF_FLG2) + n, 1u);
}

// ---------------- K5: layer-2 binary dense conv, oc-split x4 for occupancy ----------------
__global__ __launch_bounds__(256) void k_conv2(float* __restrict__ out, char* __restrict__ ws) {
    int tq = blockIdx.x / 196, bb = blockIdx.x % 196;
    int oq = tq >> 2, q = tq & 3;         // 64-oc group, 16-oc quarter
    int fp = bb * 256 + threadIdx.x;
    int n = fp / 784, pos = fp - n * 784;
    int h = pos / 28, w = pos - h * 28;
    int rt = (h == 0) ? 0 : ((h == 27) ? 2 : 1);
    int ct = (w == 0) ? 0 : ((w == 27) ? 2 : 1);
    int pat = rt * 3 + ct;
    int pb = (h + 1) * 30 + (w + 1);

    __shared__ u64   wsm[576];    // 16 oc x 36 words ([t*4+icw] per oc)
    __shared__ float c2s[144];    // 16 oc x 9 pat
    {
        const u64* wsrc = (const u64*)(ws + OFF_W2P) + (size_t)(oq * 64 + q * 16) * 36;
        for (int k = threadIdx.x; k < 576; k += 256) wsm[k] = wsrc[k];
        const float* C2 = (const float*)(ws + OFF_C2) + (oq * 64 + q * 16) * 9;
        if (threadIdx.x < 144) c2s[threadIdx.x] = C2[threadIdx.x];
    }
    const u64* ba2 = (const u64*)(ws + OFF_BA2);
    u64 aw[4][9];
#pragma unroll
    for (int icw = 0; icw < 4; icw++) {
        const u64* bp = ba2 + (size_t)(n * 4 + icw) * 900 + pb;
#pragma unroll
        for (int t = 0; t < 9; t++) { int dh = t / 3 - 1, dw = t % 3 - 1; aw[icw][t] = bp[dh * 30 + dw]; }
    }
    u32 zflag = ((const u32*)(ws + OFF_FLG2))[n];
    __syncthreads();

    const float* A2 = (const float*)(ws + OFF_A2) + oq * 64 + q * 16;   // [j]
    const float* S2 = (const float*)(ws + OFF_S2) + oq * 64 + q * 16;
    float* ob = out + ((size_t)n * 256 + oq * 64 + q * 16) * 784 + pos;
    if (!zflag) {
        float id[16];
#pragma unroll
        for (int j = 0; j < 16; j++) id[j] = ob[(size_t)j * 784];
#pragma unroll
        for (int j = 0; j < 16; j++) {
            const u64* wp = wsm + j * 36;                 // [t*4+icw]
            u32 dp0 = 0, dp1 = 0, dp2 = 0, dp3 = 0;
#pragma unroll
            for (int t = 0; t < 9; t++) {
                dp0 += (u32)__popcll(aw[0][t] ^ wp[t * 4 + 0]);
                dp1 += (u32)__popcll(aw[1][t] ^ wp[t * 4 + 1]);
                dp2 += (u32)__popcll(aw[2][t] ^ wp[t * 4 + 2]);
                dp3 += (u32)__popcll(aw[3][t] ^ wp[t * 4 + 3]);
            }
            u32 d = (dp0 + dp1) + (dp2 + dp3);
            float cf = c2s[j * 9 + pat];
            float conv = __fmaf_rn(-2.f, (float)d, cf);      // exact small integer
            float y = __fadd_rn(__fmul_rn(conv, A2[j]), S2[j]);
            float o = __fadd_rn(y, id[j]);
            o = fminf(fmaxf(o, -1.f), 1.f);
            ob[(size_t)j * 784] = o;
        }
    } else {
        const u64* bz2 = (const u64*)(ws + OFF_BZ2);
        for (int j = 0; j < 16; j++) {
            const u64* wp = wsm + j * 36;
            u32 d = 0; int cz = 0;
#pragma unroll
            for (int icw = 0; icw < 4; icw++) {
                const u64* zp = bz2 + (size_t)(n * 4 + icw) * 900 + pb;
#pragma unroll
                for (int t = 0; t < 9; t++) {
                    int dh = t / 3 - 1, dw = t % 3 - 1;
                    u64 zt = zp[dh * 30 + dw];
                    d += (u32)__popcll(aw[icw][t] ^ wp[t * 4 + icw]);
                    cz += 2 * (int)__popcll(zt & wp[t * 4 + icw]) - (int)__popcll(zt);
                }
            }
            float cf = c2s[j * 9 + pat];
            float conv = __fadd_rn(__fmaf_rn(-2.f, (float)d, cf), (float)cz);  // exact ints
            float y = __fadd_rn(__fmul_rn(conv, A2[j]), S2[j]);
            float idf = ob[(size_t)j * 784];
            float o = __fadd_rn(y, idf);
            o = fminf(fmaxf(o, -1.f), 1.f);
            ob[(size_t)j * 784] = o;
        }
    }
}

extern "C" void kernel_launch(void* const* d_in, const int* in_sizes, int n_in,
                              void* d_out, int out_size, void* d_ws, size_t ws_size,
                              hipStream_t stream) {
    const float* x  = (const float*)d_in[0];
    const float* w1 = (const float*)d_in[1];
    const float* g1 = (const float*)d_in[2];
    const float* b1 = (const float*)d_in[3];
    const float* m1 = (const float*)d_in[4];
    const float* v1 = (const float*)d_in[5];
    const float* w2 = (const float*)d_in[6];
    const float* g2 = (const float*)d_in[7];
    const float* b2 = (const float*)d_in[8];
    const float* m2 = (const float*)d_in[9];
    const float* v2 = (const float*)d_in[10];
    float* out = (float*)d_out;
    char* ws = (char*)d_ws;

    hipMemsetAsync(ws, 0, 2048, stream);   // xmax + zero-flags
    k_absmax<<<512, 256, 0, stream>>>((const float4*)x, (u32*)(ws + OFF_XMAX), NTOT / 4);
    k_prep1<<<256, 256, 0, stream>>>(w1, g1, b1, m1, v1, ws);
    k_prep2<<<64, 256, 0, stream>>>(w2, g2, b2, m2, v2, ws);
    k_pack<<<900, 256, 0, stream>>>(x, ws);
    k_conv1<<<3136, 256, 0, stream>>>(x, out, ws);
    k_conv2<<<3136, 256, 0, stream>>>(out, ws);
}